// Round 1
// baseline (304.444 us; speedup 1.0000x reference)
//
#include <hip/hip_runtime.h>
#include <hip/hip_bf16.h>

#define E_MSGS 131072
#define N_NODES 8192
#define D_DIM 256
#define XA_STRIDE 264  // 256 + 8 bf16 pad -> A-frag ds_read_b128 lands 2-way (free)

typedef __bf16 bf16x8 __attribute__((ext_vector_type(8)));
typedef float f32x4 __attribute__((ext_vector_type(4)));

// ---------------- phase 1: counting sort by node, rank by (t, id) ----------------

__global__ void k_zero(int* counts, int* cursors) {
    int i = blockIdx.x * blockDim.x + threadIdx.x;
    if (i < N_NODES) { counts[i] = 0; cursors[i] = 0; }
}

__global__ void k_count(const int* __restrict__ index, int* __restrict__ counts) {
    int e = blockIdx.x * blockDim.x + threadIdx.x;
    if (e < E_MSGS) atomicAdd(&counts[index[e]], 1);
}

// single block, 256 threads, 32 nodes/thread -> exclusive prefix sum
__global__ void k_scan(const int* __restrict__ counts, int* __restrict__ offsets) {
    __shared__ int partial[256];
    int tid = threadIdx.x;
    int base = tid * 32;
    int local[32];
    int sum = 0;
#pragma unroll
    for (int i = 0; i < 32; i++) { local[i] = sum; sum += counts[base + i]; }
    partial[tid] = sum;
    __syncthreads();
    for (int off = 1; off < 256; off <<= 1) {
        int v = (tid >= off) ? partial[tid - off] : 0;
        __syncthreads();
        partial[tid] += v;
        __syncthreads();
    }
    int basesum = (tid > 0) ? partial[tid - 1] : 0;
#pragma unroll
    for (int i = 0; i < 32; i++) offsets[base + i] = basesum + local[i];
    if (tid == 255) offsets[N_NODES] = partial[255];
}

__global__ void k_scatter(const int* __restrict__ index, const int* __restrict__ offsets,
                          int* __restrict__ cursors, int* __restrict__ bucket) {
    int e = blockIdx.x * blockDim.x + threadIdx.x;
    if (e < E_MSGS) {
        int n = index[e];
        int p = offsets[n] + atomicAdd(&cursors[n], 1);
        bucket[p] = e;
    }
}

// exact stable rank within segment: (t asc, original id asc) — matches lexsort((t,index))
__global__ void k_rank(const int* __restrict__ index, const float* __restrict__ t,
                       const int* __restrict__ offsets, const int* __restrict__ bucket,
                       int* __restrict__ sorted_id) {
    int p = blockIdx.x * blockDim.x + threadIdx.x;
    if (p < E_MSGS) {
        int e = bucket[p];
        int n = index[e];
        int beg = offsets[n], end = offsets[n + 1];
        float te = t[e];
        int r = 0;
        for (int q = beg; q < end; q++) {
            int e2 = bucket[q];
            float t2 = t[e2];
            r += (t2 < te) || (t2 == te && e2 < e);
        }
        sorted_id[beg + r] = e;
    }
}

// ---------------- phase 2: batched recurrence, 16 nodes/block, MFMA 16x16x32 bf16 ----
// W (bf16) lives entirely in registers: wave w owns outdims [64w,64w+64), 32 frags.
// h stays fp32 in registers (C/D layout). x=(m+h) round-trips LDS as bf16 each step.

__launch_bounds__(256, 2)
__global__ void k_gru(const float* __restrict__ msg, const float* __restrict__ W,
                      const float* __restrict__ b, const int* __restrict__ offsets,
                      const int* __restrict__ sorted_id, float* __restrict__ out) {
    __shared__ __bf16 xA[2][16 * XA_STRIDE];

    int tid  = threadIdx.x;
    int wave = tid >> 6;
    int lane = tid & 63;
    int q    = lane >> 4;   // quad
    int l    = lane & 15;
    int node0 = blockIdx.x * 16;

    // ---- preload W fragments (B operand: B[k][n] = W[n][k]; lane holds n=64w+16t+l,
    //      k = 32c + 8q + j) ----
    bf16x8 wf[8][4];
#pragma unroll
    for (int t4 = 0; t4 < 4; t4++) {
        const float* wr = W + (64 * wave + 16 * t4 + l) * D_DIM;
#pragma unroll
        for (int c = 0; c < 8; c++) {
            int k0 = 32 * c + 8 * q;
            float4 w0 = *(const float4*)(wr + k0);
            float4 w1 = *(const float4*)(wr + k0 + 4);
            bf16x8 f;
            f[0] = (__bf16)w0.x; f[1] = (__bf16)w0.y; f[2] = (__bf16)w0.z; f[3] = (__bf16)w0.w;
            f[4] = (__bf16)w1.x; f[5] = (__bf16)w1.y; f[6] = (__bf16)w1.z; f[7] = (__bf16)w1.w;
            wf[c][t4] = f;
        }
    }
    float bias[4];
#pragma unroll
    for (int t4 = 0; t4 < 4; t4++) bias[t4] = b[64 * wave + 16 * t4 + l];

    // per-quad node bookkeeping: quad q owns nodes 4q..4q+3 (C/D row = 4q + reg)
    int off4[4], cnt4[4];
#pragma unroll
    for (int r = 0; r < 4; r++) {
        int node = node0 + 4 * q + r;
        int o0 = offsets[node], o1 = offsets[node + 1];
        off4[r] = o0; cnt4[r] = o1 - o0;
    }
    int S = 0;
    for (int i = 0; i < 16; i++) {
        int c = offsets[node0 + i + 1] - offsets[node0 + i];
        S = max(S, c);
    }

    float h[4][4];  // [tile][reg] : (node0+4q+r, 64w+16t+l)
#pragma unroll
    for (int t4 = 0; t4 < 4; t4++)
#pragma unroll
        for (int r = 0; r < 4; r++) h[t4][r] = 0.f;

    // ---- x0 = msg0 (h=0); 0 if node empty ----
#pragma unroll
    for (int r = 0; r < 4; r++) {
        float mv[4];
        if (0 < cnt4[r]) {
            int sid = sorted_id[off4[r]];
            const float* mrow = msg + (long)sid * D_DIM;
#pragma unroll
            for (int t4 = 0; t4 < 4; t4++) mv[t4] = mrow[64 * wave + 16 * t4 + l];
        } else {
#pragma unroll
            for (int t4 = 0; t4 < 4; t4++) mv[t4] = 0.f;
        }
#pragma unroll
        for (int t4 = 0; t4 < 4; t4++)
            xA[0][(4 * q + r) * XA_STRIDE + 64 * wave + 16 * t4 + l] = (__bf16)mv[t4];
    }
    __syncthreads();

    for (int s = 0; s < S; s++) {
        const __bf16* buf = xA[s & 1];
        f32x4 acc[4];
#pragma unroll
        for (int t4 = 0; t4 < 4; t4++) acc[t4] = (f32x4){0.f, 0.f, 0.f, 0.f};
#pragma unroll
        for (int c = 0; c < 8; c++) {
            // A frag: A[m=l][k=32c+8q+j]
            bf16x8 a = *(const bf16x8*)(buf + l * XA_STRIDE + 32 * c + 8 * q);
#pragma unroll
            for (int t4 = 0; t4 < 4; t4++)
                acc[t4] = __builtin_amdgcn_mfma_f32_16x16x32_bf16(a, wf[c][t4], acc[t4], 0, 0, 0);
        }

        // gather messages for step s+1 (prefetch-ish: issued before epilogue math)
        float mv[4][4];
#pragma unroll
        for (int r = 0; r < 4; r++) {
            if (s + 1 < cnt4[r]) {
                int sid = sorted_id[off4[r] + s + 1];
                const float* mrow = msg + (long)sid * D_DIM;
#pragma unroll
                for (int t4 = 0; t4 < 4; t4++) mv[r][t4] = mrow[64 * wave + 16 * t4 + l];
            } else {
#pragma unroll
                for (int t4 = 0; t4 < 4; t4++) mv[r][t4] = 0.f;
            }
        }

        __bf16* nbuf = xA[(s + 1) & 1];
#pragma unroll
        for (int t4 = 0; t4 < 4; t4++) {
#pragma unroll
            for (int r = 0; r < 4; r++) {
                float hn = acc[t4][r] + bias[t4];
                bool valid = s < cnt4[r];
                h[t4][r] = valid ? hn : h[t4][r];
                nbuf[(4 * q + r) * XA_STRIDE + 64 * wave + 16 * t4 + l] =
                    (__bf16)(h[t4][r] + mv[r][t4]);
            }
        }
        __syncthreads();
    }

    // ---- epilogue: write fp32 h (0 for empty nodes) ----
#pragma unroll
    for (int t4 = 0; t4 < 4; t4++)
#pragma unroll
        for (int r = 0; r < 4; r++)
            out[(long)(node0 + 4 * q + r) * D_DIM + 64 * wave + 16 * t4 + l] = h[t4][r];
}

// ---------------- launch ----------------

extern "C" void kernel_launch(void* const* d_in, const int* in_sizes, int n_in,
                              void* d_out, int out_size, void* d_ws, size_t ws_size,
                              hipStream_t stream) {
    const float* msg   = (const float*)d_in[0];
    const int*   index = (const int*)d_in[1];
    const float* t     = (const float*)d_in[2];
    // d_in[3] = dim_size scalar (N_NODES, known statically)
    const float* W     = (const float*)d_in[4];
    const float* b     = (const float*)d_in[5];
    float* out = (float*)d_out;

    int* ws = (int*)d_ws;
    int* counts    = ws;               // [8192]
    int* offsets   = ws + 8192;        // [8193]
    int* cursors   = ws + 24576;       // [8192]
    int* bucket    = ws + 32768;       // [131072]
    int* sorted_id = ws + 163840;      // [131072]

    k_zero<<<N_NODES / 256, 256, 0, stream>>>(counts, cursors);
    k_count<<<E_MSGS / 256, 256, 0, stream>>>(index, counts);
    k_scan<<<1, 256, 0, stream>>>(counts, offsets);
    k_scatter<<<E_MSGS / 256, 256, 0, stream>>>(index, offsets, cursors, bucket);
    k_rank<<<E_MSGS / 256, 256, 0, stream>>>(index, t, offsets, bucket, sorted_id);
    k_gru<<<N_NODES / 16, 256, 0, stream>>>(msg, W, b, offsets, sorted_id, out);
}

// Round 2
// 262.434 us; speedup vs baseline: 1.1601x; 1.1601x over previous
//
#include <hip/hip_runtime.h>
#include <hip/hip_bf16.h>

#define E_MSGS 131072
#define N_NODES 8192
#define D_DIM 256
#define XA_STRIDE 264  // 256 + 8 bf16 pad for A-frag ds_read_b128

typedef __bf16 bf16x8 __attribute__((ext_vector_type(8)));
typedef float f32x4 __attribute__((ext_vector_type(4)));

typedef const __attribute__((address_space(1))) void cg_void;
typedef __attribute__((address_space(3))) void lds_void;

// ---------------- phase 1 ----------------

__global__ void k_count(const int* __restrict__ index, int* __restrict__ counts) {
    int e = blockIdx.x * blockDim.x + threadIdx.x;
    if (e < E_MSGS) atomicAdd(&counts[index[e]], 1);
}

// single block: exclusive scan counts->offsets AND count-desc permutation of nodes
__global__ void k_prep(const int* __restrict__ counts, int* __restrict__ offsets,
                       int* __restrict__ perm) {
    __shared__ int partial[256];
    __shared__ int hist[256];
    __shared__ int hscan[256];
    __shared__ int hcur[256];
    int tid = threadIdx.x;
    hist[tid] = 0;
    __syncthreads();

    int base = tid * 32;
    int local[32];
    int sum = 0;
#pragma unroll
    for (int i = 0; i < 32; i++) {
        local[i] = sum;
        int c = counts[base + i];
        sum += c;
        atomicAdd(&hist[min(c, 255)], 1);
    }
    partial[tid] = sum;
    __syncthreads();
    for (int off = 1; off < 256; off <<= 1) {
        int v = (tid >= off) ? partial[tid - off] : 0;
        __syncthreads();
        partial[tid] += v;
        __syncthreads();
    }
    int basesum = (tid > 0) ? partial[tid - 1] : 0;
#pragma unroll
    for (int i = 0; i < 32; i++) offsets[base + i] = basesum + local[i];
    if (tid == 255) offsets[N_NODES] = partial[255];

    // descending-count start offsets: start[c] = sum_{c'>c} hist[c']
    hscan[tid] = hist[255 - tid];
    __syncthreads();
    for (int off = 1; off < 256; off <<= 1) {
        int v = (tid >= off) ? hscan[tid - off] : 0;
        __syncthreads();
        hscan[tid] += v;
        __syncthreads();
    }
    hcur[tid] = hscan[255 - tid] - hist[tid];  // exclusive start for count value=tid
    __syncthreads();
#pragma unroll
    for (int i = 0; i < 32; i++) {
        int n = base + i;
        int c = min(counts[n], 255);
        int pos = atomicAdd(&hcur[c], 1);
        perm[pos] = n;
    }
}

__global__ void k_scatter(const int* __restrict__ index, const int* __restrict__ offsets,
                          int* __restrict__ cursors, int* __restrict__ bucket) {
    int e = blockIdx.x * blockDim.x + threadIdx.x;
    if (e < E_MSGS) {
        int n = index[e];
        int p = offsets[n] + atomicAdd(&cursors[n], 1);
        bucket[p] = e;
    }
}

// exact stable rank within segment: (t asc, original id asc) == lexsort((t, index))
__global__ void k_rank(const int* __restrict__ index, const float* __restrict__ t,
                       const int* __restrict__ offsets, const int* __restrict__ bucket,
                       int* __restrict__ sorted_id) {
    int p = blockIdx.x * blockDim.x + threadIdx.x;
    if (p < E_MSGS) {
        int e = bucket[p];
        int n = index[e];
        int beg = offsets[n], end = offsets[n + 1];
        float te = t[e];
        int r = 0;
        for (int q = beg; q < end; q++) {
            int e2 = bucket[q];
            float t2 = t[e2];
            r += (t2 < te) || (t2 == te && e2 < e);
        }
        sorted_id[beg + r] = e;
    }
}

// ---------------- phase 2: batched recurrence with async 2-deep msg pipeline ----
// 16 nodes/block (perm-grouped by count), W bf16 in registers (wave owns 64 outdims),
// h fp32 in regs (C-layout). x=(m+h) via LDS bf16. msg rows DMA'd global->LDS with
// global_load_lds (1 row = 64 lanes x 16B), gathered 2 steps ahead.

__launch_bounds__(256, 2)
__global__ void k_gru(const float* __restrict__ msg, const float* __restrict__ W,
                      const float* __restrict__ b, const int* __restrict__ offsets,
                      const int* __restrict__ sorted_id, const int* __restrict__ perm,
                      float* __restrict__ out) {
    __shared__ __bf16 xA[2][16 * XA_STRIDE];
    __shared__ float msg_lds[2][16][D_DIM];

    int tid  = threadIdx.x;
    int wave = tid >> 6;
    int lane = tid & 63;
    int q    = lane >> 4;   // quad
    int l    = lane & 15;
    int node0 = blockIdx.x * 16;

    // ---- W fragments (B operand: B[k][n]=W[n][k]; lane n=64w+16t+l, k=32c+8q+j) ----
    bf16x8 wf[8][4];
#pragma unroll
    for (int t4 = 0; t4 < 4; t4++) {
        const float* wr = W + (64 * wave + 16 * t4 + l) * D_DIM;
#pragma unroll
        for (int c = 0; c < 8; c++) {
            int k0 = 32 * c + 8 * q;
            float4 w0 = *(const float4*)(wr + k0);
            float4 w1 = *(const float4*)(wr + k0 + 4);
            bf16x8 f;
            f[0] = (__bf16)w0.x; f[1] = (__bf16)w0.y; f[2] = (__bf16)w0.z; f[3] = (__bf16)w0.w;
            f[4] = (__bf16)w1.x; f[5] = (__bf16)w1.y; f[6] = (__bf16)w1.z; f[7] = (__bf16)w1.w;
            wf[c][t4] = f;
        }
    }
    float bias[4];
#pragma unroll
    for (int t4 = 0; t4 < 4; t4++) bias[t4] = b[64 * wave + 16 * t4 + l];

    // compute-side bookkeeping: quad q owns rows 4q+r (C/D row = 4q + reg)
    int nodeC[4], off4[4], cnt4[4];
#pragma unroll
    for (int r = 0; r < 4; r++) {
        int n = perm[node0 + 4 * q + r];
        nodeC[r] = n;
        int o0 = offsets[n], o1 = offsets[n + 1];
        off4[r] = o0; cnt4[r] = o1 - o0;
    }
    int S = 0;
    for (int i = 0; i < 16; i++) {
        int n = perm[node0 + i];
        S = max(S, offsets[n + 1] - offsets[n]);
    }

    // gather-side bookkeeping: wave w DMAs rows 4w..4w+3
    int offG[4];
#pragma unroll
    for (int j = 0; j < 4; j++) offG[j] = offsets[perm[node0 + 4 * wave + j]];

    // ---- prologue: DMA m_0 -> buf0, m_1 -> buf1 ----
#pragma unroll
    for (int j = 0; j < 4; j++) {
        int sid0 = sorted_id[min(offG[j], E_MSGS - 1)];
        int sid1 = sorted_id[min(offG[j] + 1, E_MSGS - 1)];
        const float* g0 = msg + (long)sid0 * D_DIM + 4 * lane;
        const float* g1 = msg + (long)sid1 * D_DIM + 4 * lane;
        float* l0 = &msg_lds[0][4 * wave + j][4 * lane];
        float* l1 = &msg_lds[1][4 * wave + j][4 * lane];
        __builtin_amdgcn_global_load_lds((cg_void*)g0, (lds_void*)l0, 16, 0, 0);
        __builtin_amdgcn_global_load_lds((cg_void*)g1, (lds_void*)l1, 16, 0, 0);
    }
    // sid pipeline: sidg[j] = sid for msg step s+2 at loop top (s=0 -> off+2)
    int sidg[4];
#pragma unroll
    for (int j = 0; j < 4; j++) sidg[j] = sorted_id[min(offG[j] + 2, E_MSGS - 1)];
    __syncthreads();  // drains the DMA (vmcnt) + makes msg_lds visible

    // x_0 = m_0  (invalid rows: garbage, masked at commit)
    {
        int row = tid >> 4;
        int c0  = tid & 15;
#pragma unroll
        for (int k = 0; k < 16; k++) {
            int col = c0 + 16 * k;
            xA[0][row * XA_STRIDE + col] = (__bf16)msg_lds[0][row][col];
        }
    }

    float h[4][4];
#pragma unroll
    for (int t4 = 0; t4 < 4; t4++)
#pragma unroll
        for (int r = 0; r < 4; r++) h[t4][r] = 0.f;
    __syncthreads();

    for (int s = 0; s < S; s++) {
        // ---- issue DMA of m_{s+2} into msg_lds[s&1] (drained by end-of-step barrier)
#pragma unroll
        for (int j = 0; j < 4; j++) {
            const float* g = msg + (long)sidg[j] * D_DIM + 4 * lane;
            float* ld = &msg_lds[s & 1][4 * wave + j][4 * lane];
            __builtin_amdgcn_global_load_lds((cg_void*)g, (lds_void*)ld, 16, 0, 0);
        }
        // refresh sid pipeline (for step s+3; consumed next iteration)
#pragma unroll
        for (int j = 0; j < 4; j++)
            sidg[j] = sorted_id[min(offG[j] + s + 3, E_MSGS - 1)];

        // ---- MFMA: acc = x_s @ W^T ----
        const __bf16* buf = xA[s & 1];
        f32x4 acc[4];
#pragma unroll
        for (int t4 = 0; t4 < 4; t4++) acc[t4] = (f32x4){0.f, 0.f, 0.f, 0.f};
#pragma unroll
        for (int c = 0; c < 8; c++) {
            bf16x8 a = *(const bf16x8*)(buf + l * XA_STRIDE + 32 * c + 8 * q);
#pragma unroll
            for (int t4 = 0; t4 < 4; t4++)
                acc[t4] = __builtin_amdgcn_mfma_f32_16x16x32_bf16(a, wf[c][t4], acc[t4], 0, 0, 0);
        }

        // ---- epilogue: h update + x_{s+1} = h + m_{s+1} (m from LDS, DMA'd in s-1)
        __bf16* nbuf = xA[(s + 1) & 1];
        const float (*mbuf)[D_DIM] = msg_lds[(s + 1) & 1];
#pragma unroll
        for (int t4 = 0; t4 < 4; t4++) {
#pragma unroll
            for (int r = 0; r < 4; r++) {
                float hn = acc[t4][r] + bias[t4];
                bool valid = s < cnt4[r];
                h[t4][r] = valid ? hn : h[t4][r];
                float mv = mbuf[4 * q + r][64 * wave + 16 * t4 + l];
                nbuf[(4 * q + r) * XA_STRIDE + 64 * wave + 16 * t4 + l] =
                    (__bf16)(h[t4][r] + mv);
            }
        }
        __syncthreads();  // drains DMA + sid loads, publishes nbuf/msg_lds
    }

    // ---- write fp32 h (0 for empty nodes) ----
#pragma unroll
    for (int t4 = 0; t4 < 4; t4++)
#pragma unroll
        for (int r = 0; r < 4; r++)
            out[(long)nodeC[r] * D_DIM + 64 * wave + 16 * t4 + l] = h[t4][r];
}

// ---------------- launch ----------------

extern "C" void kernel_launch(void* const* d_in, const int* in_sizes, int n_in,
                              void* d_out, int out_size, void* d_ws, size_t ws_size,
                              hipStream_t stream) {
    const float* msg   = (const float*)d_in[0];
    const int*   index = (const int*)d_in[1];
    const float* t     = (const float*)d_in[2];
    const float* W     = (const float*)d_in[4];
    const float* b     = (const float*)d_in[5];
    float* out = (float*)d_out;

    int* ws = (int*)d_ws;
    int* counts    = ws;                // [8192]
    int* cursors   = ws + 8192;         // [8192] (adjacent to counts for one memset)
    int* offsets   = ws + 16384;        // [8193]
    int* perm      = ws + 24584;        // [8192]
    int* bucket    = ws + 32776;        // [131072]
    int* sorted_id = ws + 163848;       // [131072]

    hipMemsetAsync(counts, 0, 16384 * sizeof(int), stream);  // counts + cursors
    k_count<<<E_MSGS / 256, 256, 0, stream>>>(index, counts);
    k_prep<<<1, 256, 0, stream>>>(counts, offsets, perm);
    k_scatter<<<E_MSGS / 256, 256, 0, stream>>>(index, offsets, cursors, bucket);
    k_rank<<<E_MSGS / 256, 256, 0, stream>>>(index, t, offsets, bucket, sorted_id);
    k_gru<<<N_NODES / 16, 256, 0, stream>>>(msg, W, b, offsets, sorted_id, perm, out);
}